// Round 18
// baseline (175.462 us; speedup 1.0000x reference)
//
#include <hip/hip_runtime.h>
#include <hip/hip_fp16.h>
#include <cstdint>

#define NEG_SLOPE 0.2f
#define EPSV 1e-16f

#define BIN_SHIFT 7
#define NODES_PER_BIN 128
#define MAXBINS 512
#define CHUNK 2048

typedef _Float16 half8v __attribute__((ext_vector_type(8)));
typedef float float4v __attribute__((ext_vector_type(4)));
typedef int v4i __attribute__((ext_vector_type(4)));
typedef int v2i __attribute__((ext_vector_type(2)));

// CK-style raw buffer load intrinsics (32-bit voffset addressing, HW bounds check)
__device__ float buf_load_f32(v4i rsrc, int voffset, int soffset, int aux) __asm("llvm.amdgcn.raw.buffer.load.f32");
__device__ int   buf_load_i32(v4i rsrc, int voffset, int soffset, int aux) __asm("llvm.amdgcn.raw.buffer.load.i32");
__device__ v2i   buf_load_2xi32(v4i rsrc, int voffset, int soffset, int aux) __asm("llvm.amdgcn.raw.buffer.load.v2i32");

__device__ inline v4i make_rsrc(const void* p, unsigned bytes) {
    union { v4i v; struct { const void* p; unsigned range; unsigned cfg; } s; } u;
    u.s.p = p; u.s.range = bytes; u.s.cfg = 0x00020000u;  // raw dword, gfx9 config
    return u.v;
}

// ---------------- Fused: Layer 1 GEMM (MFMA) + binhist ----------------
// h1 stored SPLIT: h1h[half][n][32] fp16 (two 3.2MB arrays, 64B rows) for L2-resident gather passes.
__global__ __launch_bounds__(256) void gemm1_hist(
    const float* __restrict__ x, const float* __restrict__ W1,
    const float* __restrict__ aS, const float* __restrict__ aD,
    __half* __restrict__ h1h, float* __restrict__ as1, float* __restrict__ ad1, int N,
    const int* __restrict__ dsts, int* __restrict__ offmat,
    int E, int Et, int nbins, int nb, int gemmBlocks)
{
    __shared__ _Float16 xh[64 * 128];   // 16 KB, xh[n][k] swizzled
    __shared__ _Float16 wt[64 * 128];   // 16 KB, wt[c][k] swizzled (W transposed)
    __shared__ int lhist[MAXBINS];      // 2 KB (binhist part)
    int t = threadIdx.x;

    if ((int)blockIdx.x >= gemmBlocks) {
        // ---- binhist ----
        int blk = blockIdx.x - gemmBlocks;
        for (int i = t; i < nbins; i += 256) lhist[i] = 0;
        __syncthreads();
        int base = blk * CHUNK;
#pragma unroll
        for (int r = 0; r < CHUNK / 256; ++r) {
            int i = base + r * 256 + t;
            if (i < Et) {
                int dn = (i < E) ? dsts[i] : (i - E);
                atomicAdd(&lhist[dn >> BIN_SHIFT], 1);
            }
        }
        __syncthreads();
        for (int i = t; i < nbins; i += 256)
            offmat[(size_t)i * nb + blk] = lhist[i];
        return;
    }

    // ---- gemm1 ----
    int n0 = blockIdx.x * 64;
    const float2* x2 = (const float2*)x;
#pragma unroll
    for (int i = 0; i < 16; ++i) {
        int p = t + i * 256;            // pair index over 64*64
        int n = p >> 6, kp = p & 63;
        int gn = n0 + n;
        float2 v = (gn < N) ? x2[(size_t)gn * 64 + kp] : make_float2(0.f, 0.f);
        union { _Float16 h[2]; uint32_t u; } cv;
        cv.h[0] = (_Float16)v.x; cv.h[1] = (_Float16)v.y;
        *(uint32_t*)&xh[n * 128 + ((kp * 2) ^ ((n & 7) << 3))] = cv.u;
    }
#pragma unroll
    for (int i = 0; i < 32; ++i) {
        int p = t + i * 256;            // over 8192
        int k = p >> 6, c = p & 63;
        wt[c * 128 + (k ^ ((c & 7) << 3))] = (_Float16)W1[p];
    }
    __syncthreads();

    int wv = t >> 6, l = t & 63;
    int m0 = wv * 16;
    int lr = l & 15;
    int lg = l >> 4;
    float4v acc[4];
#pragma unroll
    for (int ct = 0; ct < 4; ++ct) acc[ct] = (float4v)(0.f);
#pragma unroll
    for (int kt = 0; kt < 4; ++kt) {
        int kh0 = kt * 32 + lg * 8;
        int an = m0 + lr;
        half8v aF = *(half8v*)&xh[an * 128 + (kh0 ^ ((an & 7) << 3))];
#pragma unroll
        for (int ct = 0; ct < 4; ++ct) {
            int c = ct * 16 + lr;
            half8v bF = *(half8v*)&wt[c * 128 + (kh0 ^ ((c & 7) << 3))];
            acc[ct] = __builtin_amdgcn_mfma_f32_16x16x32_f16(aF, bF, acc[ct], 0, 0, 0);
        }
    }
#pragma unroll
    for (int ct = 0; ct < 4; ++ct) {
        int c = ct * 16 + lr;
        float asc = aS[c], adc = aD[c];
        size_t hbase = (size_t)(c >> 5) * N * 32 + (c & 31);   // split-half layout
#pragma unroll
        for (int i = 0; i < 4; ++i) {
            int n = n0 + m0 + lg * 4 + i;
            float v = acc[ct][i];
            float s = v * asc, d = v * adc;
            s += __shfl_xor(s, 1, 64); s += __shfl_xor(s, 2, 64); s += __shfl_xor(s, 4, 64);
            d += __shfl_xor(d, 1, 64); d += __shfl_xor(d, 2, 64); d += __shfl_xor(d, 4, 64);
            if (n < N) {
                h1h[hbase + (size_t)n * 32] = __float2half(v);
                if ((l & 7) == 0) {
                    int hd = 2 * ct + ((l >> 3) & 1);
                    as1[n * 8 + hd] = s;
                    ad1[n * 8 + hd] = d;
                }
            }
        }
    }
}

// ---------------- CSR build: separate kernels (launch boundary = cheap grid barrier) ----------------
__global__ __launch_bounds__(256) void binscan2(
    int* __restrict__ offmat, int* __restrict__ bincnt, int nb)
{
    __shared__ int tsum[256];
    __shared__ int carry;
    int b = blockIdx.x, t = threadIdx.x;
    int* row = offmat + (size_t)b * nb;
    if (t == 0) carry = 0;
    __syncthreads();
    for (int base = 0; base < nb; base += 1024) {
        int i0 = base + t * 4;
        int v0 = (i0 + 0 < nb) ? row[i0 + 0] : 0;
        int v1 = (i0 + 1 < nb) ? row[i0 + 1] : 0;
        int v2 = (i0 + 2 < nb) ? row[i0 + 2] : 0;
        int v3 = (i0 + 3 < nb) ? row[i0 + 3] : 0;
        int s = v0 + v1 + v2 + v3;
        tsum[t] = s;
        __syncthreads();
        for (int off = 1; off < 256; off <<= 1) {
            int y = (t >= off) ? tsum[t - off] : 0;
            __syncthreads();
            tsum[t] += y;
            __syncthreads();
        }
        int e = tsum[t] - s + carry;
        if (i0 + 0 < nb) row[i0 + 0] = e;        e += v0;
        if (i0 + 1 < nb) row[i0 + 1] = e;        e += v1;
        if (i0 + 2 < nb) row[i0 + 2] = e;        e += v2;
        if (i0 + 3 < nb) row[i0 + 3] = e;
        __syncthreads();
        if (t == 255) carry += tsum[255];
        __syncthreads();
    }
    if (t == 0) bincnt[b] = carry;
}

__global__ __launch_bounds__(256) void binscan(
    const int* __restrict__ bincnt, int* __restrict__ binoff,
    int* __restrict__ row_ptr, int nbins, int N, int Et)
{
    __shared__ int tsum[256];
    int t = threadIdx.x;
    int i0 = t * 2;
    int v0 = (i0 + 0 < nbins) ? bincnt[i0 + 0] : 0;
    int v1 = (i0 + 1 < nbins) ? bincnt[i0 + 1] : 0;
    int s = v0 + v1;
    tsum[t] = s;
    __syncthreads();
    for (int off = 1; off < 256; off <<= 1) {
        int y = (t >= off) ? tsum[t - off] : 0;
        __syncthreads();
        tsum[t] += y;
        __syncthreads();
    }
    int e = tsum[t] - s;
    if (i0 + 0 < nbins) binoff[i0 + 0] = e;  e += v0;
    if (i0 + 1 < nbins) binoff[i0 + 1] = e;
    if (t == 255) binoff[nbins] = tsum[255];
    if (t == 0) row_ptr[N] = Et;
}

__global__ __launch_bounds__(256) void binscatter(
    const int* __restrict__ srcs, const int* __restrict__ dsts,
    const int* __restrict__ binoff, const int* __restrict__ offmat,
    unsigned int* __restrict__ binned, int E, int Et, int nbins, int nb)
{
    __shared__ int gbase[MAXBINS];
    __shared__ int lcur[MAXBINS];
    int t = threadIdx.x, blk = blockIdx.x;
    for (int i = t; i < nbins; i += 256) {
        gbase[i] = binoff[i] + offmat[(size_t)i * nb + blk];
        lcur[i] = 0;
    }
    __syncthreads();
    int base = blk * CHUNK;
#pragma unroll
    for (int r = 0; r < CHUNK / 256; ++r) {
        int i = base + r * 256 + t;
        if (i < Et) {
            int s, dn;
            if (i < E) { s = srcs[i]; dn = dsts[i]; }
            else       { s = i - E;   dn = s; }
            int b = dn >> BIN_SHIFT;
            int li = atomicAdd(&lcur[b], 1);
            binned[gbase[b] + li] = ((unsigned)(dn & (NODES_PER_BIN - 1)) << 24) | (unsigned)s;
        }
    }
}

__global__ __launch_bounds__(256) void binsort(
    const unsigned int* __restrict__ binned, const int* __restrict__ binoff,
    int* __restrict__ row_ptr, int* __restrict__ colx, int N, int nbins)
{
    __shared__ int lh[NODES_PER_BIN];
    __shared__ int lcur[NODES_PER_BIN];
    int b = blockIdx.x, t = threadIdx.x;
    int beg = binoff[b], end = binoff[b + 1];
    if (t < NODES_PER_BIN) lh[t] = 0;
    __syncthreads();
    for (int j = beg + t; j < end; j += 256)
        atomicAdd(&lh[binned[j] >> 24], 1);
    __syncthreads();
    int own = (t < NODES_PER_BIN) ? lh[t] : 0;
    for (int off = 1; off < NODES_PER_BIN; off <<= 1) {
        int y = (t >= off && t < NODES_PER_BIN) ? lh[t - off] : 0;
        __syncthreads();
        if (t < NODES_PER_BIN) lh[t] += y;
        __syncthreads();
    }
    if (t < NODES_PER_BIN) {
        int excl = lh[t] - own;
        int gnode = (b << BIN_SHIFT) + t;
        if (gnode < N) row_ptr[gnode] = beg + excl;
        lcur[t] = excl;
    }
    __syncthreads();
    for (int j = beg + t; j < end; j += 256) {
        unsigned p = binned[j];
        int pos = atomicAdd(&lcur[p >> 24], 1);
        colx[beg + pos] = (int)(p & 0xFFFFFF);
    }
}

// ---------------- Layer 1 gather: 2-pass dim-split, octet layout (8 edges/wave in flight) ----------------
// wave w in [0, 2N): pass p = (w >= N), node n = w - p*N. Pass p reads h1h[p] (3.2MB, L2-resident)
// and produces helu dims [32p, 32p+32). lane = octet o (edge slot) * 8 + sl (dim quad).
__global__ __launch_bounds__(256) void gather1(
    const int* __restrict__ row_ptr, const int* __restrict__ colx,
    const float* __restrict__ as1, const float* __restrict__ ad1,
    const __half* __restrict__ h1h, const float* __restrict__ bias1,
    float* __restrict__ helu, int N)
{
    int w = (blockIdx.x * 256 + threadIdx.x) >> 6;
    if (w >= 2 * N) return;
    int p = (w >= N) ? 1 : 0;
    int n = w - p * N;
    int lane = threadIdx.x & 63;
    int o = lane >> 3;            // octet: which edge in the 8-edge group
    int sl = lane & 7;            // dim quad within the 32-dim half
    int hh = (p << 2) + (sl >> 1);
    v4i rsH = make_rsrc(h1h + (size_t)p * N * 32, (unsigned)N * 64u);
    v4i rsA = make_rsrc(as1, (unsigned)N * 32u);
    float adn = ad1[n * 8 + hh];
    int beg = row_ptr[n], end = row_ptr[n + 1];
    float ax = 0.f, ay = 0.f, az = 0.f, aw = 0.f, ws = 0.f;
    int alhead = sl << 2;         // head byte offset for batched alpha load

    for (int cb = beg; cb < end; cb += 64) {
        int cnt = min(64, end - cb);
        int sv = (cb + lane < end) ? colx[cb + lane] : 0;
        int groups = (cnt + 7) >> 3;   // uniform across wave
        for (int g = 0; g < groups; ++g) {
            int gk = g << 3;
            int sg = __shfl(sv, gk + o, 64);
            float aV = buf_load_f32(rsA, (sg << 5) + alhead, 0, 0);  // 8 edges x 8 heads
            int k = gk + o;
            int s = __shfl(sv, k, 64);
            float a = __shfl(aV, (o << 3) + hh, 64);
            v2i hv = buf_load_2xi32(rsH, (s << 6) + (sl << 3), 0, 0);
            float ee = a + adn; ee = fmaxf(ee, NEG_SLOPE * ee);
            float wgt = (k < cnt) ? __expf(ee) : 0.f;
            union { int i; __half2 h; } u0, u1; u0.i = hv[0]; u1.i = hv[1];
            float2 f0 = __half22float2(u0.h);
            float2 f1 = __half22float2(u1.h);
            ax = fmaf(wgt, f0.x, ax); ay = fmaf(wgt, f0.y, ay);
            az = fmaf(wgt, f1.x, az); aw = fmaf(wgt, f1.y, aw);
            ws += wgt;
        }
    }
    // reduce across octets (xor 8, 16, 32)
    ax += __shfl_xor(ax, 8, 64); ax += __shfl_xor(ax, 16, 64); ax += __shfl_xor(ax, 32, 64);
    ay += __shfl_xor(ay, 8, 64); ay += __shfl_xor(ay, 16, 64); ay += __shfl_xor(ay, 32, 64);
    az += __shfl_xor(az, 8, 64); az += __shfl_xor(az, 16, 64); az += __shfl_xor(az, 32, 64);
    aw += __shfl_xor(aw, 8, 64); aw += __shfl_xor(aw, 16, 64); aw += __shfl_xor(aw, 32, 64);
    ws += __shfl_xor(ws, 8, 64); ws += __shfl_xor(ws, 16, 64); ws += __shfl_xor(ws, 32, 64);
    if (lane < 8) {
        float4 b = *(const float4*)&bias1[p * 32 + (sl << 2)];
        float inv = 1.f / (ws + EPSV);
        float v0 = ax * inv + b.x;
        float v1 = ay * inv + b.y;
        float v2 = az * inv + b.z;
        float v3 = aw * inv + b.w;
        v0 = (v0 > 0.f) ? v0 : (__expf(v0) - 1.f);
        v1 = (v1 > 0.f) ? v1 : (__expf(v1) - 1.f);
        v2 = (v2 > 0.f) ? v2 : (__expf(v2) - 1.f);
        v3 = (v3 > 0.f) ? v3 : (__expf(v3) - 1.f);
        *(float4*)&helu[(size_t)n * 64 + p * 32 + (sl << 2)] = make_float4(v0, v1, v2, v3);
    }
}

// ---------------- Layer 2 GEMM via MFMA: h2 = helu@W2 (N,64)->(N,40) + scalar alphas ----------------
__global__ __launch_bounds__(256) void gemm2_alpha(
    const float* __restrict__ helu, const float* __restrict__ W2,
    const float* __restrict__ aS, const float* __restrict__ aD,
    __half* __restrict__ h2h, float* __restrict__ as2, float* __restrict__ ad2, int N)
{
    __shared__ _Float16 xh[64 * 64];    // 8 KB
    __shared__ _Float16 wt[48 * 64];    // 6 KB (rows 40..47 zero)
    int t = threadIdx.x;
    int n0 = blockIdx.x * 64;

    for (int i = t; i < (48 * 64) / 2; i += 256) ((uint32_t*)wt)[i] = 0;
    __syncthreads();

    const float2* h2p = (const float2*)helu;
#pragma unroll
    for (int i = 0; i < 8; ++i) {
        int p = t + i * 256;
        int n = p >> 5, kp = p & 31;
        int gn = n0 + n;
        float2 v = (gn < N) ? h2p[(size_t)gn * 32 + kp] : make_float2(0.f, 0.f);
        union { _Float16 h[2]; uint32_t u; } cv;
        cv.h[0] = (_Float16)v.x; cv.h[1] = (_Float16)v.y;
        *(uint32_t*)&xh[n * 64 + ((kp * 2) ^ ((n & 7) << 3))] = cv.u;
    }
#pragma unroll
    for (int i = 0; i < 10; ++i) {
        int p = t + i * 256;
        if (p < 64 * 40) {
            int k = p / 40, c = p - k * 40;
            wt[c * 64 + (k ^ ((c & 7) << 3))] = (_Float16)W2[p];
        }
    }
    __syncthreads();

    int wv = t >> 6, l = t & 63;
    int m0 = wv * 16;
    int lr = l & 15;
    int lg = l >> 4;
    float4v acc[3];
#pragma unroll
    for (int ct = 0; ct < 3; ++ct) acc[ct] = (float4v)(0.f);
#pragma unroll
    for (int kt = 0; kt < 2; ++kt) {
        int kh0 = kt * 32 + lg * 8;
        int an = m0 + lr;
        half8v aF = *(half8v*)&xh[an * 64 + (kh0 ^ ((an & 7) << 3))];
#pragma unroll
        for (int ct = 0; ct < 3; ++ct) {
            int c = ct * 16 + lr;
            half8v bF = *(half8v*)&wt[c * 64 + (kh0 ^ ((c & 7) << 3))];
            acc[ct] = __builtin_amdgcn_mfma_f32_16x16x32_f16(aF, bF, acc[ct], 0, 0, 0);
        }
    }
    float sv[4] = {0.f, 0.f, 0.f, 0.f};
    float dv[4] = {0.f, 0.f, 0.f, 0.f};
#pragma unroll
    for (int ct = 0; ct < 3; ++ct) {
        int c = ct * 16 + lr;
        bool av = (c < 40);
        float asc = av ? aS[c] : 0.f;
        float adc = av ? aD[c] : 0.f;
#pragma unroll
        for (int i = 0; i < 4; ++i) {
            int n = n0 + m0 + lg * 4 + i;
            float v = acc[ct][i];
            sv[i] = fmaf(v, asc, sv[i]);
            dv[i] = fmaf(v, adc, dv[i]);
            if (av && n < N) h2h[(size_t)n * 64 + c] = __float2half(v);
        }
    }
#pragma unroll
    for (int i = 0; i < 4; ++i) {
        float s = sv[i], d = dv[i];
        s += __shfl_xor(s, 1, 64); s += __shfl_xor(s, 2, 64);
        s += __shfl_xor(s, 4, 64); s += __shfl_xor(s, 8, 64);
        d += __shfl_xor(d, 1, 64); d += __shfl_xor(d, 2, 64);
        d += __shfl_xor(d, 4, 64); d += __shfl_xor(d, 8, 64);
        int n = n0 + m0 + lg * 4 + i;
        if (lr == 0 && n < N) { as2[n] = s; ad2[n] = d; }
    }
}

// ---------------- Layer 2 gather: 4 edges/wave (quarter-split), 8B h loads ----------------
__global__ __launch_bounds__(256) void gather2(
    const int* __restrict__ row_ptr, const int* __restrict__ colx,
    const float* __restrict__ as2, const float* __restrict__ ad2,
    const __half* __restrict__ h2h, const float* __restrict__ bias2,
    float* __restrict__ out, int N)
{
    int wave = (blockIdx.x * 256 + threadIdx.x) >> 6;
    if (wave >= N) return;
    int lane = threadIdx.x & 63;
    int q = lane >> 4;
    int sl = lane & 15;
    int sl8 = sl << 3;
    v4i rsH = make_rsrc(h2h, (unsigned)N * 128u);
    v4i rsA = make_rsrc(as2, (unsigned)N * 4u);
    int n = wave;
    float adn = ad2[n];
    int beg = row_ptr[n], end = row_ptr[n + 1];
    float ax = 0.f, ay = 0.f, az = 0.f, aw = 0.f, ws = 0.f;

#define G2_BODY(ii) { \
    int k = ((ii) << 2) + q; \
    int s = __shfl(sv, k, 64); \
    float a = __shfl(aV, k, 64); \
    v2i hv = buf_load_2xi32(rsH, (s << 7) + sl8, 0, 0); \
    float ee = a + adn; ee = fmaxf(ee, NEG_SLOPE * ee); \
    float w = (k < cnt) ? __expf(ee) : 0.f; \
    union { int i; __half2 h; } u0, u1; u0.i = hv[0]; u1.i = hv[1]; \
    float2 f0 = __half22float2(u0.h); \
    float2 f1 = __half22float2(u1.h); \
    ax = fmaf(w, f0.x, ax); ay = fmaf(w, f0.y, ay); \
    az = fmaf(w, f1.x, az); aw = fmaf(w, f1.y, aw); \
    ws += w; }

    for (int cb = beg; cb < end; cb += 64) {
        int cnt = min(64, end - cb);
        int sv = (cb + lane < end) ? colx[cb + lane] : 0;
        float aV = buf_load_f32(rsA, sv << 2, 0, 0);
        int iters = (cnt + 3) >> 2;
        int i = 0;
        for (; i + 2 <= iters; i += 2) { G2_BODY(i) G2_BODY(i + 1) }
        for (; i < iters; ++i) { G2_BODY(i) }
    }
#undef G2_BODY

    ax += __shfl_xor(ax, 16, 64); ax += __shfl_xor(ax, 32, 64);
    ay += __shfl_xor(ay, 16, 64); ay += __shfl_xor(ay, 32, 64);
    az += __shfl_xor(az, 16, 64); az += __shfl_xor(az, 32, 64);
    aw += __shfl_xor(aw, 16, 64); aw += __shfl_xor(aw, 32, 64);
    ws += __shfl_xor(ws, 16, 64); ws += __shfl_xor(ws, 32, 64);
    if (lane < 10) {
        float4 b = *(const float4*)&bias2[sl << 2];
        float inv = 1.f / (ws + EPSV);
        *(float4*)&out[(size_t)n * 40 + (sl << 2)] =
            make_float4(ax * inv + b.x, ay * inv + b.y, az * inv + b.z, aw * inv + b.w);
    }
}

extern "C" void kernel_launch(void* const* d_in, const int* in_sizes, int n_in,
                              void* d_out, int out_size, void* d_ws, size_t ws_size,
                              hipStream_t stream)
{
    const float* x   = (const float*)d_in[0];
    const int*   ei  = (const int*)d_in[1];
    const float* W1  = (const float*)d_in[3];
    const float* aS1 = (const float*)d_in[4];
    const float* aD1 = (const float*)d_in[5];
    const float* b1  = (const float*)d_in[6];
    const float* W2  = (const float*)d_in[7];
    const float* aS2 = (const float*)d_in[8];
    const float* aD2 = (const float*)d_in[9];
    const float* b2  = (const float*)d_in[10];

    int N  = in_sizes[0] / 128;
    int E  = in_sizes[1] / 2;
    int Et = E + N;
    int nbins = (N + NODES_PER_BIN - 1) >> BIN_SHIFT;
    int nb = (Et + CHUNK - 1) / CHUNK;   // blocks for binhist/binscatter

    // ---- workspace layout ----
    float* fws   = (float*)d_ws;
    float* as1   = fws;                        // N*8
    float* ad1   = as1  + (size_t)N * 8;       // N*8
    float* helu  = ad1  + (size_t)N * 8;       // N*64
    float* as2   = helu + (size_t)N * 64;      // N
    float* ad2   = as2  + (size_t)N;           // N
    __half* h1h  = (__half*)(ad2 + (size_t)N); // 2 x N*32 halves (split halves)
    __half* h2h  = h1h + (size_t)N * 64;       // N*64 halves (stride-64 padded)
    int*   iws     = (int*)(h2h + (size_t)N * 64);
    int*   row_ptr = iws;                      // N+1
    int*   bincnt  = row_ptr + N + 1;          // MAXBINS+1
    int*   binoff  = bincnt + MAXBINS + 1;     // MAXBINS+1
    int*   offmat  = binoff + MAXBINS + 1;     // MAXBINS*nb
    unsigned int* binned = (unsigned int*)(offmat + (size_t)MAXBINS * nb);  // Et
    int*   colx    = (int*)(binned + Et);      // Et
    float* out     = (float*)d_out;

    const int* srcs = ei;
    const int* dsts = ei + E;

    int gemmBlocks = (N + 63) / 64;

    // ---- kernel A: gemm1 + binhist fused (independent block ranges, no sync) ----
    gemm1_hist<<<gemmBlocks + nb, 256, 0, stream>>>(
        x, W1, aS1, aD1, h1h, as1, ad1, N, dsts, offmat, E, Et, nbins, nb, gemmBlocks);

    // ---- CSR build (separate launches = cheap grid barriers) ----
    binscan2<<<nbins, 256, 0, stream>>>(offmat, bincnt, nb);
    binscan<<<1, 256, 0, stream>>>(bincnt, binoff, row_ptr, nbins, N, Et);
    binscatter<<<nb, 256, 0, stream>>>(srcs, dsts, binoff, offmat, binned, E, Et, nbins, nb);
    binsort<<<nbins, 256, 0, stream>>>(binned, binoff, row_ptr, colx, N, nbins);

    // ---- Layer 1 gather (2N waves, pass-major) ----
    gather1<<<(2 * N * 64 + 255) / 256, 256, 0, stream>>>(row_ptr, colx, as1, ad1,
        h1h, b1, helu, N);

    // ---- Layer 2 ----
    gemm2_alpha<<<(N + 63) / 64, 256, 0, stream>>>(helu, W2, aS2, aD2, h2h, as2, ad2, N);
    gather2<<<(N * 64 + 255) / 256, 256, 0, stream>>>(row_ptr, colx, as2, ad2,
        h2h, b2, out, N);
}

// Round 19
// 138.840 us; speedup vs baseline: 1.2638x; 1.2638x over previous
//
#include <hip/hip_runtime.h>
#include <hip/hip_fp16.h>
#include <cstdint>

#define NEG_SLOPE 0.2f
#define EPSV 1e-16f

#define BIN_SHIFT 7
#define NODES_PER_BIN 128
#define MAXBINS 512
#define CHUNK 2048

typedef _Float16 half8v __attribute__((ext_vector_type(8)));
typedef float float4v __attribute__((ext_vector_type(4)));
typedef int v4i __attribute__((ext_vector_type(4)));
typedef int v2i __attribute__((ext_vector_type(2)));

// CK-style raw buffer load intrinsics (32-bit voffset addressing, HW bounds check)
__device__ float buf_load_f32(v4i rsrc, int voffset, int soffset, int aux) __asm("llvm.amdgcn.raw.buffer.load.f32");
__device__ int   buf_load_i32(v4i rsrc, int voffset, int soffset, int aux) __asm("llvm.amdgcn.raw.buffer.load.i32");
__device__ v2i   buf_load_2xi32(v4i rsrc, int voffset, int soffset, int aux) __asm("llvm.amdgcn.raw.buffer.load.v2i32");

__device__ inline v4i make_rsrc(const void* p, unsigned bytes) {
    union { v4i v; struct { const void* p; unsigned range; unsigned cfg; } s; } u;
    u.s.p = p; u.s.range = bytes; u.s.cfg = 0x00020000u;  // raw dword, gfx9 config
    return u.v;
}

// ---------------- Fused: Layer 1 GEMM (MFMA) + binhist ----------------
// blocks [0, gemmBlocks): h1 = x@W1 + alpha logits; blocks [gemmBlocks, +nb): per-block LDS histogram.
__global__ __launch_bounds__(256) void gemm1_hist(
    const float* __restrict__ x, const float* __restrict__ W1,
    const float* __restrict__ aS, const float* __restrict__ aD,
    __half* __restrict__ h1h, float* __restrict__ as1, float* __restrict__ ad1, int N,
    const int* __restrict__ dsts, int* __restrict__ offmat,
    int E, int Et, int nbins, int nb, int gemmBlocks)
{
    __shared__ _Float16 xh[64 * 128];   // 16 KB, xh[n][k] swizzled
    __shared__ _Float16 wt[64 * 128];   // 16 KB, wt[c][k] swizzled (W transposed)
    __shared__ int lhist[MAXBINS];      // 2 KB (binhist part)
    int t = threadIdx.x;

    if ((int)blockIdx.x >= gemmBlocks) {
        // ---- binhist ----
        int blk = blockIdx.x - gemmBlocks;
        for (int i = t; i < nbins; i += 256) lhist[i] = 0;
        __syncthreads();
        int base = blk * CHUNK;
#pragma unroll
        for (int r = 0; r < CHUNK / 256; ++r) {
            int i = base + r * 256 + t;
            if (i < Et) {
                int dn = (i < E) ? dsts[i] : (i - E);
                atomicAdd(&lhist[dn >> BIN_SHIFT], 1);
            }
        }
        __syncthreads();
        for (int i = t; i < nbins; i += 256)
            offmat[(size_t)i * nb + blk] = lhist[i];
        return;
    }

    // ---- gemm1 ----
    int n0 = blockIdx.x * 64;
    const float2* x2 = (const float2*)x;
#pragma unroll
    for (int i = 0; i < 16; ++i) {
        int p = t + i * 256;            // pair index over 64*64
        int n = p >> 6, kp = p & 63;
        int gn = n0 + n;
        float2 v = (gn < N) ? x2[(size_t)gn * 64 + kp] : make_float2(0.f, 0.f);
        union { _Float16 h[2]; uint32_t u; } cv;
        cv.h[0] = (_Float16)v.x; cv.h[1] = (_Float16)v.y;
        *(uint32_t*)&xh[n * 128 + ((kp * 2) ^ ((n & 7) << 3))] = cv.u;
    }
#pragma unroll
    for (int i = 0; i < 32; ++i) {
        int p = t + i * 256;            // over 8192
        int k = p >> 6, c = p & 63;
        wt[c * 128 + (k ^ ((c & 7) << 3))] = (_Float16)W1[p];
    }
    __syncthreads();

    int wv = t >> 6, l = t & 63;
    int m0 = wv * 16;
    int lr = l & 15;
    int lg = l >> 4;
    float4v acc[4];
#pragma unroll
    for (int ct = 0; ct < 4; ++ct) acc[ct] = (float4v)(0.f);
#pragma unroll
    for (int kt = 0; kt < 4; ++kt) {
        int kh0 = kt * 32 + lg * 8;
        int an = m0 + lr;
        half8v aF = *(half8v*)&xh[an * 128 + (kh0 ^ ((an & 7) << 3))];
#pragma unroll
        for (int ct = 0; ct < 4; ++ct) {
            int c = ct * 16 + lr;
            half8v bF = *(half8v*)&wt[c * 128 + (kh0 ^ ((c & 7) << 3))];
            acc[ct] = __builtin_amdgcn_mfma_f32_16x16x32_f16(aF, bF, acc[ct], 0, 0, 0);
        }
    }
#pragma unroll
    for (int ct = 0; ct < 4; ++ct) {
        int c = ct * 16 + lr;
        float asc = aS[c], adc = aD[c];
#pragma unroll
        for (int i = 0; i < 4; ++i) {
            int n = n0 + m0 + lg * 4 + i;
            float v = acc[ct][i];
            float s = v * asc, d = v * adc;
            s += __shfl_xor(s, 1, 64); s += __shfl_xor(s, 2, 64); s += __shfl_xor(s, 4, 64);
            d += __shfl_xor(d, 1, 64); d += __shfl_xor(d, 2, 64); d += __shfl_xor(d, 4, 64);
            if (n < N) {
                h1h[(size_t)n * 64 + c] = __float2half(v);
                if ((l & 7) == 0) {
                    int hd = 2 * ct + ((l >> 3) & 1);
                    as1[n * 8 + hd] = s;
                    ad1[n * 8 + hd] = d;
                }
            }
        }
    }
}

// ---------------- CSR build: separate kernels (launch boundary = cheap grid barrier) ----------------
__global__ __launch_bounds__(256) void binscan2(
    int* __restrict__ offmat, int* __restrict__ bincnt, int nb)
{
    __shared__ int tsum[256];
    __shared__ int carry;
    int b = blockIdx.x, t = threadIdx.x;
    int* row = offmat + (size_t)b * nb;
    if (t == 0) carry = 0;
    __syncthreads();
    for (int base = 0; base < nb; base += 1024) {
        int i0 = base + t * 4;
        int v0 = (i0 + 0 < nb) ? row[i0 + 0] : 0;
        int v1 = (i0 + 1 < nb) ? row[i0 + 1] : 0;
        int v2 = (i0 + 2 < nb) ? row[i0 + 2] : 0;
        int v3 = (i0 + 3 < nb) ? row[i0 + 3] : 0;
        int s = v0 + v1 + v2 + v3;
        tsum[t] = s;
        __syncthreads();
        for (int off = 1; off < 256; off <<= 1) {
            int y = (t >= off) ? tsum[t - off] : 0;
            __syncthreads();
            tsum[t] += y;
            __syncthreads();
        }
        int e = tsum[t] - s + carry;
        if (i0 + 0 < nb) row[i0 + 0] = e;        e += v0;
        if (i0 + 1 < nb) row[i0 + 1] = e;        e += v1;
        if (i0 + 2 < nb) row[i0 + 2] = e;        e += v2;
        if (i0 + 3 < nb) row[i0 + 3] = e;
        __syncthreads();
        if (t == 255) carry += tsum[255];
        __syncthreads();
    }
    if (t == 0) bincnt[b] = carry;
}

__global__ __launch_bounds__(256) void binscan(
    const int* __restrict__ bincnt, int* __restrict__ binoff,
    int* __restrict__ row_ptr, int nbins, int N, int Et)
{
    __shared__ int tsum[256];
    int t = threadIdx.x;
    int i0 = t * 2;
    int v0 = (i0 + 0 < nbins) ? bincnt[i0 + 0] : 0;
    int v1 = (i0 + 1 < nbins) ? bincnt[i0 + 1] : 0;
    int s = v0 + v1;
    tsum[t] = s;
    __syncthreads();
    for (int off = 1; off < 256; off <<= 1) {
        int y = (t >= off) ? tsum[t - off] : 0;
        __syncthreads();
        tsum[t] += y;
        __syncthreads();
    }
    int e = tsum[t] - s;
    if (i0 + 0 < nbins) binoff[i0 + 0] = e;  e += v0;
    if (i0 + 1 < nbins) binoff[i0 + 1] = e;
    if (t == 255) binoff[nbins] = tsum[255];
    if (t == 0) row_ptr[N] = Et;
}

__global__ __launch_bounds__(256) void binscatter(
    const int* __restrict__ srcs, const int* __restrict__ dsts,
    const int* __restrict__ binoff, const int* __restrict__ offmat,
    unsigned int* __restrict__ binned, int E, int Et, int nbins, int nb)
{
    __shared__ int gbase[MAXBINS];
    __shared__ int lcur[MAXBINS];
    int t = threadIdx.x, blk = blockIdx.x;
    for (int i = t; i < nbins; i += 256) {
        gbase[i] = binoff[i] + offmat[(size_t)i * nb + blk];
        lcur[i] = 0;
    }
    __syncthreads();
    int base = blk * CHUNK;
#pragma unroll
    for (int r = 0; r < CHUNK / 256; ++r) {
        int i = base + r * 256 + t;
        if (i < Et) {
            int s, dn;
            if (i < E) { s = srcs[i]; dn = dsts[i]; }
            else       { s = i - E;   dn = s; }
            int b = dn >> BIN_SHIFT;
            int li = atomicAdd(&lcur[b], 1);
            binned[gbase[b] + li] = ((unsigned)(dn & (NODES_PER_BIN - 1)) << 24) | (unsigned)s;
        }
    }
}

__global__ __launch_bounds__(256) void binsort(
    const unsigned int* __restrict__ binned, const int* __restrict__ binoff,
    int* __restrict__ row_ptr, int* __restrict__ colx, int N, int nbins)
{
    __shared__ int lh[NODES_PER_BIN];
    __shared__ int lcur[NODES_PER_BIN];
    int b = blockIdx.x, t = threadIdx.x;
    int beg = binoff[b], end = binoff[b + 1];
    if (t < NODES_PER_BIN) lh[t] = 0;
    __syncthreads();
    for (int j = beg + t; j < end; j += 256)
        atomicAdd(&lh[binned[j] >> 24], 1);
    __syncthreads();
    int own = (t < NODES_PER_BIN) ? lh[t] : 0;
    for (int off = 1; off < NODES_PER_BIN; off <<= 1) {
        int y = (t >= off && t < NODES_PER_BIN) ? lh[t - off] : 0;
        __syncthreads();
        if (t < NODES_PER_BIN) lh[t] += y;
        __syncthreads();
    }
    if (t < NODES_PER_BIN) {
        int excl = lh[t] - own;
        int gnode = (b << BIN_SHIFT) + t;
        if (gnode < N) row_ptr[gnode] = beg + excl;
        lcur[t] = excl;
    }
    __syncthreads();
    for (int j = beg + t; j < end; j += 256) {
        unsigned p = binned[j];
        int pos = atomicAdd(&lcur[p >> 24], 1);
        colx[beg + pos] = (int)(p & 0xFFFFFF);
    }
}

// ---------------- Layer 1 gather: 4 edges/wave (quarter-split), 8B h loads ----------------
__global__ __launch_bounds__(256) void gather1(
    const int* __restrict__ row_ptr, const int* __restrict__ colx,
    const float* __restrict__ as1, const float* __restrict__ ad1,
    const __half* __restrict__ h1h, const float* __restrict__ bias1,
    float* __restrict__ helu, int N)
{
    int wave = (blockIdx.x * 256 + threadIdx.x) >> 6;
    if (wave >= N) return;
    int lane = threadIdx.x & 63;
    int q = lane >> 4;
    int sl = lane & 15;
    int hh = sl >> 1;
    int sl8 = sl << 3;
    v4i rsH = make_rsrc(h1h, (unsigned)N * 128u);
    v4i rsA = make_rsrc(as1, (unsigned)N * 32u);
    int n = wave;
    float adn = ad1[n * 8 + hh];
    int beg = row_ptr[n], end = row_ptr[n + 1];
    float ax = 0.f, ay = 0.f, az = 0.f, aw = 0.f, ws = 0.f;
    int albase = lane >> 3;
    int alhead = (lane & 7) << 2;

    for (int cb = beg; cb < end; cb += 64) {
        int cnt = min(64, end - cb);
        int sv = (cb + lane < end) ? colx[cb + lane] : 0;
        int groups = (cnt + 7) >> 3;
        for (int g = 0; g < groups; ++g) {
            int gk = g << 3;
            int sg = __shfl(sv, gk + albase, 64);
            float aV = buf_load_f32(rsA, (sg << 5) + alhead, 0, 0);
#pragma unroll
            for (int hs = 0; hs < 2; ++hs) {
                int e = (hs << 2) + q;
                int k = gk + e;
                int s = __shfl(sv, k, 64);
                float a = __shfl(aV, (e << 3) + hh, 64);
                v2i hv = buf_load_2xi32(rsH, (s << 7) + sl8, 0, 0);
                float ee = a + adn; ee = fmaxf(ee, NEG_SLOPE * ee);
                float w = (k < cnt) ? __expf(ee) : 0.f;
                union { int i; __half2 h; } u0, u1; u0.i = hv[0]; u1.i = hv[1];
                float2 f0 = __half22float2(u0.h);
                float2 f1 = __half22float2(u1.h);
                ax = fmaf(w, f0.x, ax); ay = fmaf(w, f0.y, ay);
                az = fmaf(w, f1.x, az); aw = fmaf(w, f1.y, aw);
                ws += w;
            }
        }
    }
    ax += __shfl_xor(ax, 16, 64); ax += __shfl_xor(ax, 32, 64);
    ay += __shfl_xor(ay, 16, 64); ay += __shfl_xor(ay, 32, 64);
    az += __shfl_xor(az, 16, 64); az += __shfl_xor(az, 32, 64);
    aw += __shfl_xor(aw, 16, 64); aw += __shfl_xor(aw, 32, 64);
    ws += __shfl_xor(ws, 16, 64); ws += __shfl_xor(ws, 32, 64);
    if (lane < 16) {
        float4 b = ((const float4*)bias1)[sl];
        float inv = 1.f / (ws + EPSV);
        float v0 = ax * inv + b.x;
        float v1 = ay * inv + b.y;
        float v2 = az * inv + b.z;
        float v3 = aw * inv + b.w;
        v0 = (v0 > 0.f) ? v0 : (__expf(v0) - 1.f);
        v1 = (v1 > 0.f) ? v1 : (__expf(v1) - 1.f);
        v2 = (v2 > 0.f) ? v2 : (__expf(v2) - 1.f);
        v3 = (v3 > 0.f) ? v3 : (__expf(v3) - 1.f);
        *(float4*)&helu[(size_t)n * 64 + (sl << 2)] = make_float4(v0, v1, v2, v3);
    }
}

// ---------------- Layer 2 GEMM via MFMA: h2 = helu@W2 (N,64)->(N,40) + scalar alphas ----------------
__global__ __launch_bounds__(256) void gemm2_alpha(
    const float* __restrict__ helu, const float* __restrict__ W2,
    const float* __restrict__ aS, const float* __restrict__ aD,
    __half* __restrict__ h2h, float* __restrict__ as2, float* __restrict__ ad2, int N)
{
    __shared__ _Float16 xh[64 * 64];    // 8 KB
    __shared__ _Float16 wt[48 * 64];    // 6 KB (rows 40..47 zero)
    int t = threadIdx.x;
    int n0 = blockIdx.x * 64;

    for (int i = t; i < (48 * 64) / 2; i += 256) ((uint32_t*)wt)[i] = 0;
    __syncthreads();

    const float2* h2p = (const float2*)helu;
#pragma unroll
    for (int i = 0; i < 8; ++i) {
        int p = t + i * 256;
        int n = p >> 5, kp = p & 31;
        int gn = n0 + n;
        float2 v = (gn < N) ? h2p[(size_t)gn * 32 + kp] : make_float2(0.f, 0.f);
        union { _Float16 h[2]; uint32_t u; } cv;
        cv.h[0] = (_Float16)v.x; cv.h[1] = (_Float16)v.y;
        *(uint32_t*)&xh[n * 64 + ((kp * 2) ^ ((n & 7) << 3))] = cv.u;
    }
#pragma unroll
    for (int i = 0; i < 10; ++i) {
        int p = t + i * 256;
        if (p < 64 * 40) {
            int k = p / 40, c = p - k * 40;
            wt[c * 64 + (k ^ ((c & 7) << 3))] = (_Float16)W2[p];
        }
    }
    __syncthreads();

    int wv = t >> 6, l = t & 63;
    int m0 = wv * 16;
    int lr = l & 15;
    int lg = l >> 4;
    float4v acc[3];
#pragma unroll
    for (int ct = 0; ct < 3; ++ct) acc[ct] = (float4v)(0.f);
#pragma unroll
    for (int kt = 0; kt < 2; ++kt) {
        int kh0 = kt * 32 + lg * 8;
        int an = m0 + lr;
        half8v aF = *(half8v*)&xh[an * 64 + (kh0 ^ ((an & 7) << 3))];
#pragma unroll
        for (int ct = 0; ct < 3; ++ct) {
            int c = ct * 16 + lr;
            half8v bF = *(half8v*)&wt[c * 64 + (kh0 ^ ((c & 7) << 3))];
            acc[ct] = __builtin_amdgcn_mfma_f32_16x16x32_f16(aF, bF, acc[ct], 0, 0, 0);
        }
    }
    float sv[4] = {0.f, 0.f, 0.f, 0.f};
    float dv[4] = {0.f, 0.f, 0.f, 0.f};
#pragma unroll
    for (int ct = 0; ct < 3; ++ct) {
        int c = ct * 16 + lr;
        bool av = (c < 40);
        float asc = av ? aS[c] : 0.f;
        float adc = av ? aD[c] : 0.f;
#pragma unroll
        for (int i = 0; i < 4; ++i) {
            int n = n0 + m0 + lg * 4 + i;
            float v = acc[ct][i];
            sv[i] = fmaf(v, asc, sv[i]);
            dv[i] = fmaf(v, adc, dv[i]);
            if (av && n < N) h2h[(size_t)n * 64 + c] = __float2half(v);
        }
    }
#pragma unroll
    for (int i = 0; i < 4; ++i) {
        float s = sv[i], d = dv[i];
        s += __shfl_xor(s, 1, 64); s += __shfl_xor(s, 2, 64);
        s += __shfl_xor(s, 4, 64); s += __shfl_xor(s, 8, 64);
        d += __shfl_xor(d, 1, 64); d += __shfl_xor(d, 2, 64);
        d += __shfl_xor(d, 4, 64); d += __shfl_xor(d, 8, 64);
        int n = n0 + m0 + lg * 4 + i;
        if (lr == 0 && n < N) { as2[n] = s; ad2[n] = d; }
    }
}

// ---------------- Layer 2 gather: 4 edges/wave (quarter-split), 8B h loads ----------------
__global__ __launch_bounds__(256) void gather2(
    const int* __restrict__ row_ptr, const int* __restrict__ colx,
    const float* __restrict__ as2, const float* __restrict__ ad2,
    const __half* __restrict__ h2h, const float* __restrict__ bias2,
    float* __restrict__ out, int N)
{
    int wave = (blockIdx.x * 256 + threadIdx.x) >> 6;
    if (wave >= N) return;
    int lane = threadIdx.x & 63;
    int q = lane >> 4;
    int sl = lane & 15;
    int sl8 = sl << 3;
    v4i rsH = make_rsrc(h2h, (unsigned)N * 128u);
    v4i rsA = make_rsrc(as2, (unsigned)N * 4u);
    int n = wave;
    float adn = ad2[n];
    int beg = row_ptr[n], end = row_ptr[n + 1];
    float ax = 0.f, ay = 0.f, az = 0.f, aw = 0.f, ws = 0.f;

#define G2_BODY(ii) { \
    int k = ((ii) << 2) + q; \
    int s = __shfl(sv, k, 64); \
    float a = __shfl(aV, k, 64); \
    v2i hv = buf_load_2xi32(rsH, (s << 7) + sl8, 0, 0); \
    float ee = a + adn; ee = fmaxf(ee, NEG_SLOPE * ee); \
    float w = (k < cnt) ? __expf(ee) : 0.f; \
    union { int i; __half2 h; } u0, u1; u0.i = hv[0]; u1.i = hv[1]; \
    float2 f0 = __half22float2(u0.h); \
    float2 f1 = __half22float2(u1.h); \
    ax = fmaf(w, f0.x, ax); ay = fmaf(w, f0.y, ay); \
    az = fmaf(w, f1.x, az); aw = fmaf(w, f1.y, aw); \
    ws += w; }

    for (int cb = beg; cb < end; cb += 64) {
        int cnt = min(64, end - cb);
        int sv = (cb + lane < end) ? colx[cb + lane] : 0;
        float aV = buf_load_f32(rsA, sv << 2, 0, 0);
        int iters = (cnt + 3) >> 2;
        int i = 0;
        for (; i + 2 <= iters; i += 2) { G2_BODY(i) G2_BODY(i + 1) }
        for (; i < iters; ++i) { G2_BODY(i) }
    }
#undef G2_BODY

    ax += __shfl_xor(ax, 16, 64); ax += __shfl_xor(ax, 32, 64);
    ay += __shfl_xor(ay, 16, 64); ay += __shfl_xor(ay, 32, 64);
    az += __shfl_xor(az, 16, 64); az += __shfl_xor(az, 32, 64);
    aw += __shfl_xor(aw, 16, 64); aw += __shfl_xor(aw, 32, 64);
    ws += __shfl_xor(ws, 16, 64); ws += __shfl_xor(ws, 32, 64);
    if (lane < 10) {
        float4 b = *(const float4*)&bias2[sl << 2];
        float inv = 1.f / (ws + EPSV);
        *(float4*)&out[(size_t)n * 40 + (sl << 2)] =
            make_float4(ax * inv + b.x, ay * inv + b.y, az * inv + b.z, aw * inv + b.w);
    }
}

extern "C" void kernel_launch(void* const* d_in, const int* in_sizes, int n_in,
                              void* d_out, int out_size, void* d_ws, size_t ws_size,
                              hipStream_t stream)
{
    const float* x   = (const float*)d_in[0];
    const int*   ei  = (const int*)d_in[1];
    const float* W1  = (const float*)d_in[3];
    const float* aS1 = (const float*)d_in[4];
    const float* aD1 = (const float*)d_in[5];
    const float* b1  = (const float*)d_in[6];
    const float* W2  = (const float*)d_in[7];
    const float* aS2 = (const float*)d_in[8];
    const float* aD2 = (const float*)d_in[9];
    const float* b2  = (const float*)d_in[10];

    int N  = in_sizes[0] / 128;
    int E  = in_sizes[1] / 2;
    int Et = E + N;
    int nbins = (N + NODES_PER_BIN - 1) >> BIN_SHIFT;
    int nb = (Et + CHUNK - 1) / CHUNK;   // blocks for binhist/binscatter

    // ---- workspace layout ----
    float* fws   = (float*)d_ws;
    float* as1   = fws;                        // N*8
    float* ad1   = as1  + (size_t)N * 8;       // N*8
    float* helu  = ad1  + (size_t)N * 8;       // N*64
    float* as2   = helu + (size_t)N * 64;      // N
    float* ad2   = as2  + (size_t)N;           // N
    __half* h1h  = (__half*)(ad2 + (size_t)N); // N*64 halves
    __half* h2h  = h1h + (size_t)N * 64;       // N*64 halves (stride-64 padded)
    int*   iws     = (int*)(h2h + (size_t)N * 64);
    int*   row_ptr = iws;                      // N+1
    int*   bincnt  = row_ptr + N + 1;          // MAXBINS+1
    int*   binoff  = bincnt + MAXBINS + 1;     // MAXBINS+1
    int*   offmat  = binoff + MAXBINS + 1;     // MAXBINS*nb
    unsigned int* binned = (unsigned int*)(offmat + (size_t)MAXBINS * nb);  // Et
    int*   colx    = (int*)(binned + Et);      // Et
    float* out     = (float*)d_out;

    const int* srcs = ei;
    const int* dsts = ei + E;

    int gemmBlocks = (N + 63) / 64;

    // ---- kernel A: gemm1 + binhist fused (independent block ranges, no sync) ----
    gemm1_hist<<<gemmBlocks + nb, 256, 0, stream>>>(
        x, W1, aS1, aD1, h1h, as1, ad1, N, dsts, offmat, E, Et, nbins, nb, gemmBlocks);

    // ---- CSR build (separate launches = cheap grid barriers) ----
    binscan2<<<nbins, 256, 0, stream>>>(offmat, bincnt, nb);
    binscan<<<1, 256, 0, stream>>>(bincnt, binoff, row_ptr, nbins, N, Et);
    binscatter<<<nb, 256, 0, stream>>>(srcs, dsts, binoff, offmat, binned, E, Et, nbins, nb);
    binsort<<<nbins, 256, 0, stream>>>(binned, binoff, row_ptr, colx, N, nbins);

    // ---- Layer 1 gather ----
    gather1<<<(N * 64 + 255) / 256, 256, 0, stream>>>(row_ptr, colx, as1, ad1,
        h1h, b1, helu, N);

    // ---- Layer 2 ----
    gemm2_alpha<<<(N + 63) / 64, 256, 0, stream>>>(helu, W2, aS2, aD2, h2h, as2, ad2, N);
    gather2<<<(N * 64 + 255) / 256, 256, 0, stream>>>(row_ptr, colx, as2, ad2,
        h2h, b2, out, N);
}